// Round 7
// baseline (134.890 us; speedup 1.0000x reference)
//
#include <hip/hip_runtime.h>
#include <hip/hip_bf16.h>

typedef __bf16 bf16x8 __attribute__((ext_vector_type(8)));
typedef float f32x4 __attribute__((ext_vector_type(4)));

#define NB 8
#define NT 2048
#define NC 1024
#define NH 64

__device__ __forceinline__ unsigned short bfbits(float f) {
    return __builtin_bit_cast(unsigned short, (__bf16)f);
}

// ---------------- kernel 1: W -> W^T (bf16) ----------------
// Wt layout: [3][64][1024], order 0=Wq, 1=Wk, 2=Wv
__global__ __launch_bounds__(256) void wt_kernel(const float* __restrict__ Wq,
                                                 const float* __restrict__ Wk,
                                                 const float* __restrict__ Wv,
                                                 unsigned short* __restrict__ Wt) {
    int idx = blockIdx.x * 256 + threadIdx.x;   // 0 .. 196608
    int n = idx >> 16;
    int r = idx & 65535;
    int c = r >> 6;       // 0..1023
    int h = r & 63;       // coalesced reads over h
    const float* W = (n == 0) ? Wq : ((n == 1) ? Wk : Wv);
    float x = W[c * 64 + h];
    Wt[(n << 16) + h * 1024 + c] = bfbits(x);
}

// ---------------- kernel 2: streaming reg-staged QKV projection ----------------
// block = 4 waves, BM=64, BK=256 (4 chunks), phase-staggered.
// Each wave reads its 16 rows' chunk as 16 x 1KB FULLY-CONTIGUOUS loads
// (global_load_dwordx4: 64 lanes x 16B = one whole row-chunk), cvt fp32->bf16
// in regs, ds_write into a single 32KB swizzled bf16 tile. Loads for chunk
// c+1 stay in flight across compute(c) (regs are the second buffer).
// W fragments read directly from L2-resident Wt (no LDS for W).
__global__ __launch_bounds__(256, 4) void proj_kernel(const float* __restrict__ Xv,
                                                      const float* __restrict__ Xk,
                                                      const float* __restrict__ Xq,
                                                      const unsigned short* __restrict__ Wt,
                                                      unsigned short* __restrict__ Q,
                                                      unsigned short* __restrict__ K,
                                                      unsigned short* __restrict__ VT) {
    __shared__ __align__(16) char Xs[64 * 512];   // 32KB: [64 rows][256 bf16]

    int type = blockIdx.x >> 8;          // 0=Q,1=K,2=V
    int mt   = blockIdx.x & 255;
    int row0 = mt << 6;
    int phase = mt & 3;                  // k-chunk rotation across blocks
    const float* X = (type == 0) ? Xq : ((type == 1) ? Xk : Xv);
    const unsigned short* W = Wt + (type << 16);

    int tid  = threadIdx.x;
    int w    = tid >> 6;
    int lane = tid & 63;
    int lo = lane & 15, hi = lane >> 4;

    // wave's 16-row slab; lane reads 16B at offset 16*lane within each 1KB row-chunk
    const char* Xw = (const char*)X + (size_t)(row0 + 16 * w) * 4096 + 16 * lane;

    float4 xr[16];
    f32x4 acc[4];
#pragma unroll
    for (int ct = 0; ct < 4; ++ct) acc[ct] = 0.f;

    // prologue: issue chunk 'phase'
#pragma unroll
    for (int i = 0; i < 16; ++i)
        xr[i] = *(const float4*)(Xw + (size_t)i * 4096 + phase * 1024);
    __builtin_amdgcn_sched_barrier(0);

    for (int c = 0; c < 4; ++c) {
        int kc = (c + phase) & 3;
        asm volatile("s_waitcnt vmcnt(0)" ::: "memory");   // xr for chunk c landed
        __builtin_amdgcn_s_barrier();                      // all waves done reading Xs
        __builtin_amdgcn_sched_barrier(0);
        // cvt + swizzled ds_write of chunk c
#pragma unroll
        for (int i = 0; i < 16; ++i) {
            int r = 16 * w + i;
            ushort4 bv;
            bv.x = bfbits(xr[i].x); bv.y = bfbits(xr[i].y);
            bv.z = bfbits(xr[i].z); bv.w = bfbits(xr[i].w);
            *(ushort4*)(Xs + r * 512 + ((8 * lane) ^ ((i & 7) << 4))) = bv;
        }
        // issue chunk c+1 (in flight across compute(c))
        if (c < 3) {
            int kn = (c + 1 + phase) & 3;
#pragma unroll
            for (int i = 0; i < 16; ++i)
                xr[i] = *(const float4*)(Xw + (size_t)i * 4096 + kn * 1024);
        }
        __builtin_amdgcn_sched_barrier(0);
        asm volatile("s_waitcnt lgkmcnt(0)" ::: "memory");  // own ds_writes done
        __builtin_amdgcn_s_barrier();                       // tile visible to all
        __builtin_amdgcn_sched_barrier(0);
        // compute chunk kc: 8 k-steps x 4 col-tiles
        const char* xrow = Xs + (16 * w + lo) * 512;
        const unsigned short* wp = W + lo * 1024 + kc * 256 + hi * 8;
#pragma unroll
        for (int ks = 0; ks < 8; ++ks) {
            bf16x8 af = *(const bf16x8*)(xrow + ((ks * 64 + hi * 16) ^ ((lo & 7) << 4)));
#pragma unroll
            for (int ct = 0; ct < 4; ++ct) {
                bf16x8 bf = *(const bf16x8*)(wp + ct * 16 * 1024 + ks * 32);
                acc[ct] = __builtin_amdgcn_mfma_f32_16x16x32_bf16(af, bf, acc[ct], 0, 0, 0);
            }
        }
    }

    // ---- epilogue ----
    if (type < 2) {
        unsigned short* O = (type == 0) ? Q : K;
#pragma unroll
        for (int ct = 0; ct < 4; ++ct)
#pragma unroll
            for (int r = 0; r < 4; ++r) {
                int row = row0 + w * 16 + hi * 4 + r;
                int h = lo + 16 * ct;
                O[(size_t)row * NH + h] = bfbits(acc[ct][r]);
            }
    } else {
        int trow = row0 + w * 16 + hi * 4;       // 4-aligned
        int b = trow >> 11;
        int t = trow & 2047;
#pragma unroll
        for (int ct = 0; ct < 4; ++ct) {
            int h = lo + 16 * ct;
            ushort4 pk;
            pk.x = bfbits(acc[ct][0]);
            pk.y = bfbits(acc[ct][1]);
            pk.z = bfbits(acc[ct][2]);
            pk.w = bfbits(acc[ct][3]);
            *(ushort4*)(VT + (size_t)(b * NH + h) * NT + t) = pk;
        }
    }
}

// ---------------- kernel 3: causal flash attention (MFMA) ----------------
// block = 4 waves, one 16-row Q-tile, 4-way split of the s-range + LDS merge
__global__ __launch_bounds__(256) void attn_kernel(const unsigned short* __restrict__ Q,
                                                   const unsigned short* __restrict__ K,
                                                   const unsigned short* __restrict__ VT,
                                                   float* __restrict__ out) {
    __shared__ __align__(16) unsigned short p_lds[4 * 512];   // per-wave 16x32 bf16 P
    __shared__ __align__(16) float acc_lds[4 * 16 * 64];
    __shared__ float m_lds[4][16];
    __shared__ float l_lds[4][16];

    int b  = blockIdx.x >> 7;
    int qt = blockIdx.x & 127;
    int q0 = qt << 4;
    int w    = threadIdx.x >> 6;
    int lane = threadIdx.x & 63;
    int lo = lane & 15, hi = lane >> 4;

    const unsigned short* qb = Q + (size_t)(b * NT + q0 + lo) * NH + hi * 8;
    bf16x8 qf0 = *(const bf16x8*)(qb);
    bf16x8 qf1 = *(const bf16x8*)(qb + 32);

    int Ctot = (q0 + 16 + 31) >> 5;              // ceil((q0+16)/32) 32-wide s-chunks
    int c0 = (Ctot * w) >> 2;
    int c1 = (Ctot * (w + 1)) >> 2;

    float m[4], l[4];
    f32x4 acc[4];
#pragma unroll
    for (int r = 0; r < 4; ++r) { m[r] = -1e30f; l[r] = 0.f; }
#pragma unroll
    for (int ct = 0; ct < 4; ++ct) acc[ct] = 0.f;

    const float SC = 0.03125f * 1.44269504088896340736f;  // (C^-0.5) * log2(e)
    unsigned short* pl = p_lds + w * 512;

    for (int c = c0; c < c1; ++c) {
        int s0 = c << 5;
        const unsigned short* kb = K + (size_t)(b * NT + s0 + lo) * NH + hi * 8;
        f32x4 S0 = 0.f, S1 = 0.f;
        S0 = __builtin_amdgcn_mfma_f32_16x16x32_bf16(qf0, *(const bf16x8*)(kb), S0, 0, 0, 0);
        S0 = __builtin_amdgcn_mfma_f32_16x16x32_bf16(qf1, *(const bf16x8*)(kb + 32), S0, 0, 0, 0);
        S1 = __builtin_amdgcn_mfma_f32_16x16x32_bf16(qf0, *(const bf16x8*)(kb + 16 * NH), S1, 0, 0, 0);
        S1 = __builtin_amdgcn_mfma_f32_16x16x32_bf16(qf1, *(const bf16x8*)(kb + 16 * NH + 32), S1, 0, 0, 0);

        int s_a = s0 + lo, s_b = s0 + 16 + lo;
        float z0[4], z1[4], mt[4];
#pragma unroll
        for (int r = 0; r < 4; ++r) {
            int qi = q0 + hi * 4 + r;
            z0[r] = (s_a <= qi) ? S0[r] * SC : -1e30f;
            z1[r] = (s_b <= qi) ? S1[r] * SC : -1e30f;
            mt[r] = fmaxf(z0[r], z1[r]);
        }
#pragma unroll
        for (int d = 1; d < 16; d <<= 1)
#pragma unroll
            for (int r = 0; r < 4; ++r)
                mt[r] = fmaxf(mt[r], __shfl_xor(mt[r], d, 16));

        float p0[4], p1[4], rs[4];
#pragma unroll
        for (int r = 0; r < 4; ++r) {
            float mn = fmaxf(m[r], mt[r]);
            float al = exp2f(m[r] - mn);
            int qi = q0 + hi * 4 + r;
            p0[r] = (s_a <= qi) ? exp2f(z0[r] - mn) : 0.f;
            p1[r] = (s_b <= qi) ? exp2f(z1[r] - mn) : 0.f;
            rs[r] = p0[r] + p1[r];
            m[r] = mn;
            l[r] *= al;
            acc[0][r] *= al; acc[1][r] *= al; acc[2][r] *= al; acc[3][r] *= al;
        }
#pragma unroll
        for (int d = 1; d < 16; d <<= 1)
#pragma unroll
            for (int r = 0; r < 4; ++r)
                rs[r] += __shfl_xor(rs[r], d, 16);
#pragma unroll
        for (int r = 0; r < 4; ++r) {
            l[r] += rs[r];
            int ql = hi * 4 + r;
            pl[ql * 32 + lo]      = bfbits(p0[r]);
            pl[ql * 32 + 16 + lo] = bfbits(p1[r]);
        }
        // P transpose via wave-private LDS -> PV A-frag (compiler inserts lgkmcnt)
        bf16x8 pa = *(const bf16x8*)(pl + lo * 32 + hi * 8);
        const unsigned short* vb = VT + (size_t)(b * NH + lo) * NT + s0 + hi * 8;
#pragma unroll
        for (int ct = 0; ct < 4; ++ct) {
            bf16x8 vv = *(const bf16x8*)(vb + ct * 16 * NT);
            acc[ct] = __builtin_amdgcn_mfma_f32_16x16x32_bf16(pa, vv, acc[ct], 0, 0, 0);
        }
    }

    // dump per-wave partial state
#pragma unroll
    for (int r = 0; r < 4; ++r) {
        int ql = hi * 4 + r;
#pragma unroll
        for (int ct = 0; ct < 4; ++ct)
            acc_lds[(w * 16 + ql) * 64 + lo + 16 * ct] = acc[ct][r];
    }
    if (lo == 0) {
#pragma unroll
        for (int r = 0; r < 4; ++r) {
            m_lds[w][hi * 4 + r] = m[r];
            l_lds[w][hi * 4 + r] = l[r];
        }
    }
    __syncthreads();

    // merge 4 s-splits: thread -> (q, 4 h's)
    int q  = threadIdx.x >> 4;
    int h0 = (threadIdx.x & 15) << 2;
    float M = fmaxf(fmaxf(m_lds[0][q], m_lds[1][q]), fmaxf(m_lds[2][q], m_lds[3][q]));
    float L = 0.f;
    float ox = 0.f, oy = 0.f, oz = 0.f, ow = 0.f;
#pragma unroll
    for (int ww = 0; ww < 4; ++ww) {
        float a_ = exp2f(m_lds[ww][q] - M);
        L += a_ * l_lds[ww][q];
        const float* p = acc_lds + (ww * 16 + q) * 64 + h0;
        ox += a_ * p[0]; oy += a_ * p[1]; oz += a_ * p[2]; ow += a_ * p[3];
    }
    float inv = 1.0f / L;
    float4 res = make_float4(ox * inv, oy * inv, oz * inv, ow * inv);
    *(float4*)(out + (size_t)(b * NT + q0 + q) * NH + h0) = res;
}

extern "C" void kernel_launch(void* const* d_in, const int* in_sizes, int n_in,
                              void* d_out, int out_size, void* d_ws, size_t ws_size,
                              hipStream_t stream) {
    const float* values  = (const float*)d_in[0];
    const float* keys    = (const float*)d_in[1];
    const float* queries = (const float*)d_in[2];
    const float* Wk = (const float*)d_in[3];
    const float* Wq = (const float*)d_in[4];
    const float* Wv = (const float*)d_in[5];
    float* out = (float*)d_out;

    unsigned short* Wt = (unsigned short*)d_ws;        // 196608 ushorts
    unsigned short* Qb = Wt + 196608;                  // Q,K,VT: 3x1048576 ushorts
    unsigned short* Kb = Qb + 1048576;
    unsigned short* VT = Kb + 1048576;

    wt_kernel<<<768, 256, 0, stream>>>(Wq, Wk, Wv, Wt);
    proj_kernel<<<768, 256, 0, stream>>>(values, keys, queries, Wt, Qb, Kb, VT);
    attn_kernel<<<1024, 256, 0, stream>>>(Qb, Kb, VT, out);
}